// Round 4
// baseline (308.850 us; speedup 1.0000x reference)
//
#include <hip/hip_runtime.h>
#include <math.h>

#define DMODEL 2048
#define NEXP   8
#define RANK   16
#define NPAIR  28   // unordered expert pairs C(8,2)
#define MAXT32 320  // >= sum ceil(n_p/32) <= 256+28

// ---------------- K1: router (logits -> top2 -> pair buckets) ----------------
// Transposed Wr in LDS ([e][d], conflict-free b128 reads, broadcast across tokens).
// 32 tokens/block, 2 tokens per lane-column (16 j-lanes x 16 token-units).
__global__ __launch_bounds__(256, 2)
void router_kernel(const float* __restrict__ x,
                   const float* __restrict__ Wr,
                   const float* __restrict__ br,
                   float2* __restrict__ wparams,
                   int* __restrict__ cnt,
                   unsigned short* __restrict__ lists,
                   int nTok)
{
    __shared__ float wr_t[NEXP][DMODEL];   // 64 KB, transposed
    const int tid = threadIdx.x;
    // stage + transpose: float4 of Wr covers (d, e0..e0+3); scatter 4 scalars.
    // write banks: bank = d mod 32; even/odd lane pairs share d (2-way = free).
    #pragma unroll
    for (int i = 0; i < 16; ++i) {
        const int f = (i*256 + tid)*4;
        const int d = f >> 3;
        const int e0 = f & 7;          // 0 or 4
        const float4 v = *(const float4*)&Wr[f];
        wr_t[e0+0][d] = v.x;
        wr_t[e0+1][d] = v.y;
        wr_t[e0+2][d] = v.z;
        wr_t[e0+3][d] = v.w;
    }
    __syncthreads();

    const int j  = tid & 15;         // d-lane 0..15
    const int su = tid >> 4;         // token unit 0..15 (2 tokens each)
    const int tok0 = blockIdx.x*32 + su*2;
    const int tok1 = tok0 + 1;
    const bool v0 = tok0 < nTok, v1 = tok1 < nTok;
    const float* xr0 = x + (size_t)(v0 ? tok0 : 0) * DMODEL;
    const float* xr1 = x + (size_t)(v1 ? tok1 : 0) * DMODEL;

    float pa[NEXP], pb[NEXP];
    #pragma unroll
    for (int e = 0; e < NEXP; ++e) { pa[e] = 0.f; pb[e] = 0.f; }

    for (int i = 0; i < 32; ++i) {
        const int d0 = (i*16 + j)*4;
        const float4 xa = *(const float4*)&xr0[d0];
        const float4 xb = *(const float4*)&xr1[d0];
        #pragma unroll
        for (int e = 0; e < NEXP; ++e) {
            const float4 wv = *(const float4*)&wr_t[e][d0];  // bank = j*4: conflict-free
            pa[e] = fmaf(xa.x, wv.x, pa[e]);
            pa[e] = fmaf(xa.y, wv.y, pa[e]);
            pa[e] = fmaf(xa.z, wv.z, pa[e]);
            pa[e] = fmaf(xa.w, wv.w, pa[e]);
            pb[e] = fmaf(xb.x, wv.x, pb[e]);
            pb[e] = fmaf(xb.y, wv.y, pb[e]);
            pb[e] = fmaf(xb.z, wv.z, pb[e]);
            pb[e] = fmaf(xb.w, wv.w, pb[e]);
        }
    }
    // butterfly across the 16 j-lanes
    #pragma unroll
    for (int mres = 1; mres < 16; mres <<= 1) {
        #pragma unroll
        for (int e = 0; e < NEXP; ++e) {
            pa[e] += __shfl_xor(pa[e], mres);
            pb[e] += __shfl_xor(pb[e], mres);
        }
    }

    if (j == 0) {
        #pragma unroll
        for (int tt = 0; tt < 2; ++tt) {
            const int tok = tt ? tok1 : tok0;
            if (tok >= nTok) continue;
            float lg[NEXP];
            #pragma unroll
            for (int e = 0; e < NEXP; ++e) lg[e] = (tt ? pb[e] : pa[e]) + br[e];
            int b0 = 0; float w0 = lg[0];
            #pragma unroll
            for (int e = 1; e < NEXP; ++e) { if (lg[e] > w0) { w0 = lg[e]; b0 = e; } }
            int b1 = (b0 == 0) ? 1 : 0; float w1 = lg[b1];
            #pragma unroll
            for (int e = 0; e < NEXP; ++e) { if (e != b0 && lg[e] > w1) { w1 = lg[e]; b1 = e; } }
            const float t = expf(w1 - w0);
            const float wtop = 1.f / (1.f + t);
            const float wsec = t / (1.f + t);
            const int lo = (b0 < b1) ? b0 : b1;
            const int hi = (b0 < b1) ? b1 : b0;
            const float wlo = (b0 < b1) ? wtop : wsec;
            const float whi = (b0 < b1) ? wsec : wtop;
            wparams[tok] = make_float2(wlo, whi);
            const int pidx = lo*(NEXP-1) - (lo*(lo-1))/2 + (hi - lo - 1);
            const int pos = atomicAdd(&cnt[pidx], 1);
            lists[(size_t)pidx*nTok + pos] = (unsigned short)tok;
        }
    }
}

// ---------------- K1.5: tile-offset prefix sums ----------------
__global__ void prefix_kernel(const int* __restrict__ cnt,
                              int* __restrict__ to32)
{
    if (threadIdx.x == 0) {
        int a32 = 0;
        for (int p = 0; p < NPAIR; ++p) {
            to32[p] = a32;
            a32 += (cnt[p] + 31) >> 5;
        }
        to32[NPAIR] = a32;
    }
}

// ---------------- K2: down projection, LDS-free streaming ----------------
// lane = (token, expert, r-quad): complete dot product in-lane; no LDS, no barriers.
// Wd reads broadcast across 32 token-lanes; each Wd d-row = one 64B line shared
// by the 4 rq-waves of the block.
__global__ __launch_bounds__(256, 2)
void down_kernel(const float* __restrict__ x,
                 const float* __restrict__ Wd,
                 const float* __restrict__ bd,
                 const float2* __restrict__ wparams,
                 const int* __restrict__ to32,
                 const int* __restrict__ cnt,
                 const unsigned short* __restrict__ lists,
                 float* __restrict__ hw,
                 int nTok)
{
    const int bx = blockIdx.x;
    if (bx >= to32[NPAIR]) return;
    int p = 0;
    while (to32[p+1] <= bx) ++p;
    const int tile = bx - to32[p];
    const int m = min(32, cnt[p] - tile*32);
    int lo = 0, rem = p;
    while (rem >= (NEXP-1-lo)) { rem -= (NEXP-1-lo); ++lo; }
    const int hi = lo + 1 + rem;

    const int tid = threadIdx.x;
    const int ts = tid & 31;          // token slot
    const int k  = (tid >> 5) & 1;    // expert slot
    const int rq = tid >> 6;          // r-quad 0..3
    const int e  = k ? hi : lo;
    const bool valid = ts < m;
    const int tok = lists[(size_t)p*nTok + tile*32 + (valid ? ts : 0)];

    const float* xp = x + (size_t)tok * DMODEL;
    const float* wp = Wd + (size_t)e * (DMODEL*RANK) + rq*4;

    float ax = 0.f, ay = 0.f, az = 0.f, aw = 0.f;
    #pragma unroll 4
    for (int dc = 0; dc < DMODEL/4; ++dc) {
        const int d = dc*4;
        const float4 xv = *(const float4*)&xp[d];
        const float4 w0 = *(const float4*)&wp[(d+0)*RANK];
        const float4 w1 = *(const float4*)&wp[(d+1)*RANK];
        const float4 w2 = *(const float4*)&wp[(d+2)*RANK];
        const float4 w3 = *(const float4*)&wp[(d+3)*RANK];
        ax = fmaf(xv.x, w0.x, ax); ax = fmaf(xv.y, w1.x, ax);
        ax = fmaf(xv.z, w2.x, ax); ax = fmaf(xv.w, w3.x, ax);
        ay = fmaf(xv.x, w0.y, ay); ay = fmaf(xv.y, w1.y, ay);
        ay = fmaf(xv.z, w2.y, ay); ay = fmaf(xv.w, w3.y, ay);
        az = fmaf(xv.x, w0.z, az); az = fmaf(xv.y, w1.z, az);
        az = fmaf(xv.z, w2.z, az); az = fmaf(xv.w, w3.z, az);
        aw = fmaf(xv.x, w0.w, aw); aw = fmaf(xv.y, w1.w, aw);
        aw = fmaf(xv.z, w2.w, aw); aw = fmaf(xv.w, w3.w, aw);
    }

    const float2 wp2 = wparams[tok];
    const float w = k ? wp2.y : wp2.x;
    const float4 bdv = *(const float4*)&bd[e*RANK + rq*4];
    float4 h;
    h.x = fmaxf(ax + bdv.x, 0.f) * w;
    h.y = fmaxf(ay + bdv.y, 0.f) * w;
    h.z = fmaxf(az + bdv.z, 0.f) * w;
    h.w = fmaxf(aw + bdv.w, 0.f) * w;
    if (valid) {
        *(float4*)&hw[(size_t)tok*32 + k*16 + rq*4] = h;
    }
}

// ---------------- K3: up projection: out[t][d] = sum_kr hw[t][kr]*Wu + w.bu ----------------
__global__ __launch_bounds__(256, 2)
void up_kernel(const float* __restrict__ Wu,
               const float* __restrict__ bu,
               const float2* __restrict__ wparams,
               const int* __restrict__ cnt,
               const int* __restrict__ to32,
               const unsigned short* __restrict__ lists,
               const float* __restrict__ hw,
               float* __restrict__ out,
               int nTok)
{
    const int bx = blockIdx.x;
    if (bx >= to32[NPAIR]) return;
    int p = 0;
    while (to32[p+1] <= bx) ++p;
    const int tile = bx - to32[p];
    const int m = min(32, cnt[p] - tile*32);
    int lo = 0, rem = p;
    while (rem >= (NEXP-1-lo)) { rem -= (NEXP-1-lo); ++lo; }
    const int hi = lo + 1 + rem;
    const int cc = blockIdx.y;        // d-chunk of 256

    __shared__ float wu_lds[2][16][256];   // 32 KB
    __shared__ float h_lds[32][36];        // 4.6 KB
    __shared__ float w2_lds[2][32];
    __shared__ int   tok_lds[32];

    const int tid = threadIdx.x;

    if (tid < 32) {
        const int idx = tile*32 + ((tid < m) ? tid : 0);
        const int t = lists[(size_t)p*nTok + idx];
        tok_lds[tid] = t;
        const float2 w = wparams[t];
        w2_lds[0][tid] = (tid < m) ? w.x : 0.f;
        w2_lds[1][tid] = (tid < m) ? w.y : 0.f;
    }

    // stage Wu chunk: direct global->LDS
    #pragma unroll
    for (int i = 0; i < 8; ++i) {
        const int f  = i*1024 + tid*4;   // 0..8191
        const int kk = f >> 12;
        const int rr = (f >> 8) & 15;
        const int dd = f & 255;
        const int es = kk ? hi : lo;
        *(float4*)&wu_lds[kk][rr][dd] =
            *(const float4*)&Wu[(size_t)es*(RANK*DMODEL) + (size_t)rr*DMODEL + cc*256 + dd];
    }
    __syncthreads();

    {   // gather h' (1 float4 per thread; needs tok_lds)
        const int tk = tid >> 3, o = (tid & 7) * 4;
        const float4 hv = *(const float4*)&hw[(size_t)tok_lds[tk]*32 + o];
        *(float4*)&h_lds[tk][o] = hv;
    }
    __syncthreads();

    const int dg = tid & 31;    // 32 d-groups (4 floats each, two halves)
    const int tq = tid >> 5;    // 8 token quads
    float4 a0[4], a1[4];
    #pragma unroll
    for (int i = 0; i < 4; ++i) { a0[i] = make_float4(0,0,0,0); a1[i] = make_float4(0,0,0,0); }

    #pragma unroll 8
    for (int kr = 0; kr < 32; ++kr) {
        const int kk = kr >> 4, rr = kr & 15;
        const float4 u0 = *(const float4*)&wu_lds[kk][rr][dg*4];
        const float4 u1 = *(const float4*)&wu_lds[kk][rr][128 + dg*4];
        #pragma unroll
        for (int i = 0; i < 4; ++i) {
            const float hv = h_lds[tq*4 + i][kr];
            a0[i].x = fmaf(hv, u0.x, a0[i].x);
            a0[i].y = fmaf(hv, u0.y, a0[i].y);
            a0[i].z = fmaf(hv, u0.z, a0[i].z);
            a0[i].w = fmaf(hv, u0.w, a0[i].w);
            a1[i].x = fmaf(hv, u1.x, a1[i].x);
            a1[i].y = fmaf(hv, u1.y, a1[i].y);
            a1[i].z = fmaf(hv, u1.z, a1[i].z);
            a1[i].w = fmaf(hv, u1.w, a1[i].w);
        }
    }

    const float4 bl0 = *(const float4*)&bu[(size_t)lo*DMODEL + cc*256 + dg*4];
    const float4 bl1 = *(const float4*)&bu[(size_t)lo*DMODEL + cc*256 + 128 + dg*4];
    const float4 bh0 = *(const float4*)&bu[(size_t)hi*DMODEL + cc*256 + dg*4];
    const float4 bh1 = *(const float4*)&bu[(size_t)hi*DMODEL + cc*256 + 128 + dg*4];

    #pragma unroll
    for (int i = 0; i < 4; ++i) {
        const int slot = tq*4 + i;
        if (slot < m) {
            const int t = tok_lds[slot];
            const float wl = w2_lds[0][slot];
            const float wh = w2_lds[1][slot];
            float4 o0 = a0[i], o1 = a1[i];
            o0.x += wl*bl0.x + wh*bh0.x;  o0.y += wl*bl0.y + wh*bh0.y;
            o0.z += wl*bl0.z + wh*bh0.z;  o0.w += wl*bl0.w + wh*bh0.w;
            o1.x += wl*bl1.x + wh*bh1.x;  o1.y += wl*bl1.y + wh*bh1.y;
            o1.z += wl*bl1.z + wh*bh1.z;  o1.w += wl*bl1.w + wh*bh1.w;
            float* op = &out[(size_t)t*DMODEL + cc*256];
            *(float4*)&op[dg*4]       = o0;
            *(float4*)&op[128 + dg*4] = o1;
        }
    }
}

extern "C" void kernel_launch(void* const* d_in, const int* in_sizes, int n_in,
                              void* d_out, int out_size, void* d_ws, size_t ws_size,
                              hipStream_t stream)
{
    (void)n_in; (void)out_size; (void)ws_size;
    const float* x  = (const float*)d_in[0];
    const float* Wr = (const float*)d_in[1];
    const float* br = (const float*)d_in[2];
    const float* Wd = (const float*)d_in[3];
    const float* bd = (const float*)d_in[4];
    const float* Wu = (const float*)d_in[5];
    const float* bu = (const float*)d_in[6];
    float* out = (float*)d_out;
    const int nTok = in_sizes[0] / DMODEL;   // 8192

    // ws layout: [0,112) cnt | [256,372) to32 | [512,..) wparams | lists | hw
    char* base = (char*)d_ws;
    int* cnt  = (int*)(base);
    int* to32 = (int*)(base + 256);
    float2* wparams = (float2*)(base + 512);
    size_t off = 512 + (size_t)nTok*sizeof(float2);
    unsigned short* lists = (unsigned short*)(base + off);
    off += (size_t)NPAIR*nTok*sizeof(unsigned short);
    off = (off + 255) & ~(size_t)255;
    float* hw = (float*)(base + off);

    hipMemsetAsync(d_ws, 0, 512, stream);
    const int ntiles = (nTok + 31)/32;
    router_kernel<<<ntiles, 256, 0, stream>>>(x, Wr, br, wparams, cnt, lists, nTok);
    prefix_kernel<<<1, 64, 0, stream>>>(cnt, to32);
    down_kernel<<<MAXT32, 256, 0, stream>>>(x, Wd, bd, wparams, to32, cnt, lists, hw, nTok);
    dim3 gup(MAXT32, 8);
    up_kernel<<<gup, 256, 0, stream>>>(Wu, bu, wparams, cnt, to32, lists, hw, out, nTok);
}

// Round 5
// 149.359 us; speedup vs baseline: 2.0678x; 2.0678x over previous
//
#include <hip/hip_runtime.h>
#include <math.h>

#define DMODEL 2048
#define NEXP   8
#define RANK   16
#define NPAIR  28   // unordered expert pairs C(8,2)
#define MAXT16 576  // >= sum ceil(n_p/16) <= 512+28
#define MAXT32 320  // >= sum ceil(n_p/32) <= 256+28

// ---------------- K1: router (logits -> top2 -> pair buckets) ----------------
// 16 tokens/block (grid 512). lane = (d-quad dg, expert-pair ep, token-octet th).
// Wr read straight from L2 (64 KB, hot); x b128 coalesced; no big LDS.
__global__ __launch_bounds__(256, 2)
void router_kernel(const float* __restrict__ x,
                   const float* __restrict__ Wr,
                   const float* __restrict__ br,
                   float2* __restrict__ wparams,
                   int* __restrict__ cnt,
                   unsigned short* __restrict__ lists,
                   int nTok)
{
    __shared__ float lg_lds[16][8];

    const int tid = threadIdx.x;
    const int dg  = tid & 31;       // d-quad lane: covers d = it*128 + dg*4 .. +3
    const int grp = tid >> 5;       // 0..7
    const int ep  = grp & 3;        // experts 2ep, 2ep+1
    const int th  = grp >> 2;       // token octet 0..1
    const int tbase = blockIdx.x*16 + th*8;

    float a0[8], a1[8];
    #pragma unroll
    for (int t = 0; t < 8; ++t) { a0[t] = 0.f; a1[t] = 0.f; }

    for (int it = 0; it < 16; ++it) {
        const int d0 = it*128 + dg*4;
        const float2 w0 = *(const float2*)&Wr[(d0+0)*NEXP + ep*2];
        const float2 w1 = *(const float2*)&Wr[(d0+1)*NEXP + ep*2];
        const float2 w2 = *(const float2*)&Wr[(d0+2)*NEXP + ep*2];
        const float2 w3 = *(const float2*)&Wr[(d0+3)*NEXP + ep*2];
        #pragma unroll
        for (int t = 0; t < 8; ++t) {
            const float4 xv = *(const float4*)&x[(size_t)(tbase+t)*DMODEL + d0];
            a0[t] = fmaf(xv.x, w0.x, a0[t]);
            a0[t] = fmaf(xv.y, w1.x, a0[t]);
            a0[t] = fmaf(xv.z, w2.x, a0[t]);
            a0[t] = fmaf(xv.w, w3.x, a0[t]);
            a1[t] = fmaf(xv.x, w0.y, a1[t]);
            a1[t] = fmaf(xv.y, w1.y, a1[t]);
            a1[t] = fmaf(xv.z, w2.y, a1[t]);
            a1[t] = fmaf(xv.w, w3.y, a1[t]);
        }
    }
    // butterfly allreduce over the 32 dg-lanes (stays within each 32-lane half)
    #pragma unroll
    for (int mm = 1; mm <= 16; mm <<= 1) {
        #pragma unroll
        for (int t = 0; t < 8; ++t) {
            a0[t] += __shfl_xor(a0[t], mm);
            a1[t] += __shfl_xor(a1[t], mm);
        }
    }
    if (dg < 8) {   // lane dg publishes token dg of this octet
        lg_lds[th*8 + dg][ep*2 + 0] = a0[dg];
        lg_lds[th*8 + dg][ep*2 + 1] = a1[dg];
    }
    __syncthreads();

    if (tid < 16) {
        const int tok = blockIdx.x*16 + tid;
        if (tok < nTok) {
            float lg[NEXP];
            #pragma unroll
            for (int e = 0; e < NEXP; ++e) lg[e] = lg_lds[tid][e] + br[e];
            int b0 = 0; float v0 = lg[0];
            #pragma unroll
            for (int e = 1; e < NEXP; ++e) { if (lg[e] > v0) { v0 = lg[e]; b0 = e; } }
            int b1 = (b0 == 0) ? 1 : 0; float v1 = lg[b1];
            #pragma unroll
            for (int e = 0; e < NEXP; ++e) { if (e != b0 && lg[e] > v1) { v1 = lg[e]; b1 = e; } }
            const float t = expf(v1 - v0);
            const float wtop = 1.f / (1.f + t);
            const float wsec = t / (1.f + t);
            const int lo = (b0 < b1) ? b0 : b1;
            const int hi = (b0 < b1) ? b1 : b0;
            const float wlo = (b0 < b1) ? wtop : wsec;
            const float whi = (b0 < b1) ? wsec : wtop;
            wparams[tok] = make_float2(wlo, whi);
            const int pidx = lo*(NEXP-1) - (lo*(lo-1))/2 + (hi - lo - 1);
            const int pos = atomicAdd(&cnt[pidx], 1);
            lists[(size_t)pidx*nTok + pos] = (unsigned short)tok;
        }
    }
}

// ---------------- K1.5: tile-offset prefix sums ----------------
__global__ void prefix_kernel(const int* __restrict__ cnt,
                              int* __restrict__ to16,
                              int* __restrict__ to32)
{
    if (threadIdx.x == 0) {
        int a16 = 0, a32 = 0;
        for (int p = 0; p < NPAIR; ++p) {
            to16[p] = a16; to32[p] = a32;
            a16 += (cnt[p] + 15) >> 4;
            a32 += (cnt[p] + 31) >> 5;
        }
        to16[NPAIR] = a16; to32[NPAIR] = a32;
    }
}

// ---------------- K2: down projection, coalesced streaming, no LDS ----------------
// Raw partial dots: hw2[t][ch][k][r] = sum_{d in ch half} x[t][d]*Wd[e_k][d][r].
// lane = (dg = d mod 32, token-quad tq, expert k). x: 128B coalesced per half-wave.
// Wd: 4x b128 rows, 32 lanes span 2KB contiguous. Grid (tiles16, 2 c-halves).
__global__ __launch_bounds__(256, 2)
void down_kernel(const float* __restrict__ x,
                 const float* __restrict__ Wd,
                 const int* __restrict__ cnt,
                 const int* __restrict__ to16,
                 const unsigned short* __restrict__ lists,
                 float* __restrict__ hw2,
                 int nTok)
{
    const int bx = blockIdx.x;
    if (bx >= to16[NPAIR]) return;
    int p = 0;
    while (to16[p+1] <= bx) ++p;
    const int tile = bx - to16[p];
    const int m = min(16, cnt[p] - tile*16);
    int lo = 0, rem = p;
    while (rem >= (NEXP-1-lo)) { rem -= (NEXP-1-lo); ++lo; }
    const int hi = lo + 1 + rem;
    const int ch = blockIdx.y;         // c-half 0/1

    const int tid = threadIdx.x;
    const int dg = tid & 31;
    const int tq = (tid >> 5) & 3;
    const int k  = tid >> 7;
    const int e  = k ? hi : lo;

    int toks[4];
    #pragma unroll
    for (int i = 0; i < 4; ++i) {
        const int slot = tq*4 + i;
        toks[i] = lists[(size_t)p*nTok + tile*16 + ((slot < m) ? slot : 0)];
    }

    const float* wdp = Wd + (size_t)e * (DMODEL*RANK);

    float acc[4][16];
    #pragma unroll
    for (int i = 0; i < 4; ++i)
        #pragma unroll
        for (int r = 0; r < 16; ++r) acc[i][r] = 0.f;

    const int dbase = ch*1024 + dg;
    #pragma unroll 2
    for (int jj = 0; jj < 32; ++jj) {
        const int d = dbase + jj*32;
        const float4 w0 = *(const float4*)&wdp[d*RANK + 0];
        const float4 w1 = *(const float4*)&wdp[d*RANK + 4];
        const float4 w2 = *(const float4*)&wdp[d*RANK + 8];
        const float4 w3 = *(const float4*)&wdp[d*RANK + 12];
        float xv[4];
        #pragma unroll
        for (int i = 0; i < 4; ++i) xv[i] = x[(size_t)toks[i]*DMODEL + d];
        #pragma unroll
        for (int i = 0; i < 4; ++i) {
            acc[i][0]  = fmaf(xv[i], w0.x, acc[i][0]);
            acc[i][1]  = fmaf(xv[i], w0.y, acc[i][1]);
            acc[i][2]  = fmaf(xv[i], w0.z, acc[i][2]);
            acc[i][3]  = fmaf(xv[i], w0.w, acc[i][3]);
            acc[i][4]  = fmaf(xv[i], w1.x, acc[i][4]);
            acc[i][5]  = fmaf(xv[i], w1.y, acc[i][5]);
            acc[i][6]  = fmaf(xv[i], w1.z, acc[i][6]);
            acc[i][7]  = fmaf(xv[i], w1.w, acc[i][7]);
            acc[i][8]  = fmaf(xv[i], w2.x, acc[i][8]);
            acc[i][9]  = fmaf(xv[i], w2.y, acc[i][9]);
            acc[i][10] = fmaf(xv[i], w2.z, acc[i][10]);
            acc[i][11] = fmaf(xv[i], w2.w, acc[i][11]);
            acc[i][12] = fmaf(xv[i], w3.x, acc[i][12]);
            acc[i][13] = fmaf(xv[i], w3.y, acc[i][13]);
            acc[i][14] = fmaf(xv[i], w3.z, acc[i][14]);
            acc[i][15] = fmaf(xv[i], w3.w, acc[i][15]);
        }
    }

    // butterfly allreduce over the 32 dg-lanes
    #pragma unroll
    for (int mm = 1; mm <= 16; mm <<= 1)
        #pragma unroll
        for (int i = 0; i < 4; ++i)
            #pragma unroll
            for (int r = 0; r < 16; ++r)
                acc[i][r] += __shfl_xor(acc[i][r], mm);

    // writers: dg<16 -> (i = dg>>2, rq = dg&3)
    if (dg < 16) {
        const int i  = dg >> 2;
        const int rq = dg & 3;
        const int slot = tq*4 + i;
        if (slot < m) {
            float4 v;
            v.x = acc[i][rq*4+0];
            v.y = acc[i][rq*4+1];
            v.z = acc[i][rq*4+2];
            v.w = acc[i][rq*4+3];
            *(float4*)&hw2[(size_t)toks[i]*64 + ch*32 + k*16 + rq*4] = v;
        }
    }
}

// ---------------- K3: up projection (finalizes h inline) ----------------
__global__ __launch_bounds__(256, 2)
void up_kernel(const float* __restrict__ Wu,
               const float* __restrict__ bu,
               const float* __restrict__ bd,
               const float2* __restrict__ wparams,
               const int* __restrict__ cnt,
               const int* __restrict__ to32,
               const unsigned short* __restrict__ lists,
               const float* __restrict__ hw2,
               float* __restrict__ out,
               int nTok)
{
    const int bx = blockIdx.x;
    if (bx >= to32[NPAIR]) return;
    int p = 0;
    while (to32[p+1] <= bx) ++p;
    const int tile = bx - to32[p];
    const int m = min(32, cnt[p] - tile*32);
    int lo = 0, rem = p;
    while (rem >= (NEXP-1-lo)) { rem -= (NEXP-1-lo); ++lo; }
    const int hi = lo + 1 + rem;
    const int cc = blockIdx.y;        // d-chunk of 256

    __shared__ float wu_lds[2][16][256];   // 32 KB
    __shared__ float h_lds[32][36];        // 4.6 KB
    __shared__ float w2_lds[2][32];
    __shared__ int   tok_lds[32];

    const int tid = threadIdx.x;

    if (tid < 32) {
        const int idx = tile*32 + ((tid < m) ? tid : 0);
        const int t = lists[(size_t)p*nTok + idx];
        tok_lds[tid] = t;
        const float2 w = wparams[t];
        w2_lds[0][tid] = (tid < m) ? w.x : 0.f;
        w2_lds[1][tid] = (tid < m) ? w.y : 0.f;
    }

    // stage Wu chunk: direct global->LDS
    #pragma unroll
    for (int i = 0; i < 8; ++i) {
        const int f  = i*1024 + tid*4;   // 0..8191
        const int kk = f >> 12;
        const int rr = (f >> 8) & 15;
        const int dd = f & 255;
        const int es = kk ? hi : lo;
        *(float4*)&wu_lds[kk][rr][dd] =
            *(const float4*)&Wu[(size_t)es*(RANK*DMODEL) + (size_t)rr*DMODEL + cc*256 + dd];
    }
    __syncthreads();

    {   // gather + finalize h' = relu(sum of c-half partials + bd) * w
        const int t8 = tid >> 3;          // token slot 0..31
        const int kk = (tid >> 2) & 1;
        const int rq = tid & 3;
        const int e2 = kk ? hi : lo;
        const float* hp = &hw2[(size_t)tok_lds[t8]*64 + kk*16 + rq*4];
        const float4 s0 = *(const float4*)&hp[0];
        const float4 s1 = *(const float4*)&hp[32];
        const float4 bdv = *(const float4*)&bd[e2*RANK + rq*4];
        const float w = w2_lds[kk][t8];
        float4 h;
        h.x = fmaxf(s0.x + s1.x + bdv.x, 0.f) * w;
        h.y = fmaxf(s0.y + s1.y + bdv.y, 0.f) * w;
        h.z = fmaxf(s0.z + s1.z + bdv.z, 0.f) * w;
        h.w = fmaxf(s0.w + s1.w + bdv.w, 0.f) * w;
        *(float4*)&h_lds[t8][kk*16 + rq*4] = h;
    }
    __syncthreads();

    const int dg = tid & 31;    // 32 d-groups (4 floats each, two halves)
    const int tq = tid >> 5;    // 8 token quads
    float4 a0[4], a1[4];
    #pragma unroll
    for (int i = 0; i < 4; ++i) { a0[i] = make_float4(0,0,0,0); a1[i] = make_float4(0,0,0,0); }

    #pragma unroll 8
    for (int kr = 0; kr < 32; ++kr) {
        const int kk = kr >> 4, rr = kr & 15;
        const float4 u0 = *(const float4*)&wu_lds[kk][rr][dg*4];
        const float4 u1 = *(const float4*)&wu_lds[kk][rr][128 + dg*4];
        #pragma unroll
        for (int i = 0; i < 4; ++i) {
            const float hv = h_lds[tq*4 + i][kr];
            a0[i].x = fmaf(hv, u0.x, a0[i].x);
            a0[i].y = fmaf(hv, u0.y, a0[i].y);
            a0[i].z = fmaf(hv, u0.z, a0[i].z);
            a0[i].w = fmaf(hv, u0.w, a0[i].w);
            a1[i].x = fmaf(hv, u1.x, a1[i].x);
            a1[i].y = fmaf(hv, u1.y, a1[i].y);
            a1[i].z = fmaf(hv, u1.z, a1[i].z);
            a1[i].w = fmaf(hv, u1.w, a1[i].w);
        }
    }

    const float4 bl0 = *(const float4*)&bu[(size_t)lo*DMODEL + cc*256 + dg*4];
    const float4 bl1 = *(const float4*)&bu[(size_t)lo*DMODEL + cc*256 + 128 + dg*4];
    const float4 bh0 = *(const float4*)&bu[(size_t)hi*DMODEL + cc*256 + dg*4];
    const float4 bh1 = *(const float4*)&bu[(size_t)hi*DMODEL + cc*256 + 128 + dg*4];

    #pragma unroll
    for (int i = 0; i < 4; ++i) {
        const int slot = tq*4 + i;
        if (slot < m) {
            const int t = tok_lds[slot];
            const float wl = w2_lds[0][slot];
            const float wh = w2_lds[1][slot];
            float4 o0 = a0[i], o1 = a1[i];
            o0.x += wl*bl0.x + wh*bh0.x;  o0.y += wl*bl0.y + wh*bh0.y;
            o0.z += wl*bl0.z + wh*bh0.z;  o0.w += wl*bl0.w + wh*bh0.w;
            o1.x += wl*bl1.x + wh*bh1.x;  o1.y += wl*bl1.y + wh*bh1.y;
            o1.z += wl*bl1.z + wh*bh1.z;  o1.w += wl*bl1.w + wh*bh1.w;
            float* op = &out[(size_t)t*DMODEL + cc*256];
            *(float4*)&op[dg*4]       = o0;
            *(float4*)&op[128 + dg*4] = o1;
        }
    }
}

extern "C" void kernel_launch(void* const* d_in, const int* in_sizes, int n_in,
                              void* d_out, int out_size, void* d_ws, size_t ws_size,
                              hipStream_t stream)
{
    (void)n_in; (void)out_size; (void)ws_size;
    const float* x  = (const float*)d_in[0];
    const float* Wr = (const float*)d_in[1];
    const float* br = (const float*)d_in[2];
    const float* Wd = (const float*)d_in[3];
    const float* bd = (const float*)d_in[4];
    const float* Wu = (const float*)d_in[5];
    const float* bu = (const float*)d_in[6];
    float* out = (float*)d_out;
    const int nTok = in_sizes[0] / DMODEL;   // 8192

    // ws layout: [0,112) cnt | [128,..) to16 | [256,..) to32 | [512,..) wparams
    //            | lists (u16 [28][nTok]) | hw2 (nTok*64 f32, 256B-aligned)
    char* base = (char*)d_ws;
    int* cnt  = (int*)(base);
    int* to16 = (int*)(base + 128);
    int* to32 = (int*)(base + 256);
    float2* wparams = (float2*)(base + 512);
    size_t off = 512 + (size_t)nTok*sizeof(float2);
    unsigned short* lists = (unsigned short*)(base + off);
    off += (size_t)NPAIR*nTok*sizeof(unsigned short);
    off = (off + 255) & ~(size_t)255;
    float* hw2 = (float*)(base + off);

    hipMemsetAsync(d_ws, 0, 512, stream);
    const int ntiles16 = (nTok + 15)/16;
    router_kernel<<<ntiles16, 256, 0, stream>>>(x, Wr, br, wparams, cnt, lists, nTok);
    prefix_kernel<<<1, 64, 0, stream>>>(cnt, to16, to32);
    dim3 gdown(MAXT16, 2);
    down_kernel<<<gdown, 256, 0, stream>>>(x, Wd, cnt, to16, lists, hw2, nTok);
    dim3 gup(MAXT32, 8);
    up_kernel<<<gup, 256, 0, stream>>>(Wu, bu, bd, wparams, cnt, to32, lists, hw2, out, nTok);
}